// Round 10
// baseline (136.800 us; speedup 1.0000x reference)
//
#include <hip/hip_runtime.h>
#include <hip/hip_bf16.h>
#include <hip/hip_fp16.h>

// ModulatedDeformConv2d forward: f16 NHWC x, XCD-swizzled,
// producer/consumer wave-specialized fused sample+MFMA.
// R19: block halved to 256 threads (2 producer + 2 consumer waves) on a
// 32-px tile, grid 4096, LDS 13.8 KB, launch_bounds(256,8) (VGPR<=64):
// up to 8 blocks/CU co-resident (was ~2) -> 3-4x independent gather
// chains per SIMD to hide the ~500cy scattered-gather latency that
// R17/R18 identified as the residual bound (TA util ~37%, occupancy 31%).
// Consumer waves own 32 outputs x 32 px (8 MFMA/tap, 4 ds_read, 4
// prefetched A-frag loads -- proven overlap-free in R18).
// x[8,64,128,128] f32, offset[8,18,128,128], mask[8,9,128,128],
// weight[64,64,3,3], bias[64]; out[8,64,128,128] f32.

constexpr int B    = 8;
constexpr int C    = 64;
constexpr int H    = 128;
constexpr int W    = 128;
constexpr int COUT = 64;
constexpr int K2   = 9;
constexpr int HW   = H * W;
constexpr int TPX  = 32;   // pixels per tile

typedef __attribute__((ext_vector_type(8))) short    short8;
typedef __attribute__((ext_vector_type(8))) _Float16 f16x8;
typedef __attribute__((ext_vector_type(4))) float    f32x4;

// LDS tile row: 64 ch padded to 72 halves (144 B).
constexpr int LDSS = 72;

// Raw workgroup barrier: drain LDS ops only (no vmcnt(0) drain).
#define LDS_BARRIER() asm volatile("s_waitcnt lgkmcnt(0)\n\ts_barrier" ::: "memory")

// ---------- x: NCHW f32 -> NHWC f16 ----------
__global__ __launch_bounds__(256) void transpose_x_kernel(
    const float* __restrict__ x, short* __restrict__ xt) {
    __shared__ float tbuf[64][65];
    const int blk  = blockIdx.x;          // B * (HW/64) = 2048
    const int b    = blk >> 8;
    const int hwb  = (blk & 255) * 64;
    const int lane = threadIdx.x & 63;
    const int grp  = threadIdx.x >> 6;    // 0..3
    const float* xb = x + (size_t)b * C * HW;
#pragma unroll
    for (int r = 0; r < 16; ++r) {
        const int c = grp * 16 + r;
        tbuf[c][lane] = xb[c * HW + hwb + lane];   // coalesced along hw
    }
    __syncthreads();
    short* xo = xt + (size_t)b * HW * C;
#pragma unroll
    for (int r = 0; r < 16; ++r) {
        const int hw_l = grp * 16 + r;
        union { __half h; short s; } u;
        u.h = __float2half(tbuf[lane][hw_l]);
        xo[(size_t)(hwb + hw_l) * C + lane] = u.s;  // coalesced along c
    }
}

// ---------- weight[o][c][3][3] f32 -> A-fragment-ordered f16 ----------
// wfrag[(k*8 + kk*4 + mt)*64 + lane][j] = f16( w[m][c][k] )
//   m = mt*16 + (lane&15), q = lane>>4, c = kk*32 + q*8 + j
__global__ __launch_bounds__(256) void pack_w_kernel(
    const float* __restrict__ w, short* __restrict__ wfrag) {
    int id = blockIdx.x * blockDim.x + threadIdx.x;
    if (id >= COUT * C * K2) return;
    const int j    = id & 7;
    const int lane = (id >> 3) & 63;
    const int mt   = (id >> 9) & 3;
    const int kk   = (id >> 11) & 1;
    const int k    = id >> 12;
    const int m    = mt * 16 + (lane & 15);
    const int q    = lane >> 4;
    const int c    = kk * 32 + q * 8 + j;
    union { __half h; short s; } u;
    u.h = __float2half(w[(m * C + c) * K2 + k]);
    wfrag[id] = u.s;
}

// ---------- producer/consumer fused kernel ----------
// grid 4096: b = wg&7 (XCD round-robin -> per-XCD-L2-resident f16 x),
// t = wg>>3 -> (ho, 32-px quarter-row). 256 threads = 4 waves.
__global__ __launch_bounds__(256, 8) void mdcn_pc_kernel(
    const short* __restrict__ xt,      // [B][H][W][C] f16
    const float* __restrict__ offset,
    const float* __restrict__ mask,
    const short* __restrict__ wfrag,
    const float* __restrict__ bias,
    float* __restrict__ out) {

    __shared__ short   smem[2][TPX * LDSS];  // 2 x 4608 B
    __shared__ ushort4 pidx[K2 * TPX];       // 2304 B: 4 corner linear indices
    __shared__ uint2   pwts[K2 * TPX];       // 2304 B: 4 blend wts as half4

    const int wg   = blockIdx.x;
    const int b    = wg & 7;
    const int t    = wg >> 3;                // 0..511
    const int ho   = t >> 2;
    const int px0  = (t & 3) * TPX;

    const int tid  = threadIdx.x;
    const int wave = tid >> 6;

    // ---- precompute ALL taps' sampling params (one thread per (tap,px)) ----
    for (int f = tid; f < K2 * TPX; f += 256) {
        const int k = f >> 5;                // tap
        const int i = f & 31;                // tile-local pixel
        const int wo = px0 + i;
        const int ky = k / 3, kx = k % 3;
        const float dx = offset[(((size_t)b * 2 * K2 + 2 * k    ) * H + ho) * W + wo];
        const float dy = offset[(((size_t)b * 2 * K2 + 2 * k + 1) * H + ho) * W + wo];
        const float mm = mask  [(((size_t)b * K2     + k        ) * H + ho) * W + wo];
        const float py = (float)(ho - 1 + ky) + dy;
        const float px = (float)(wo - 1 + kx) + dx;
        const float y0f = floorf(py), x0f = floorf(px);
        const float wy1 = py - y0f,   wx1 = px - x0f;
        const float wy0 = 1.0f - wy1, wx0 = 1.0f - wx1;
        const int iy0 = (int)y0f, ix0 = (int)x0f;
        const int iy1 = iy0 + 1,  ix1 = ix0 + 1;
        const bool vy0 = (iy0 >= 0) & (iy0 < H);
        const bool vy1 = (iy1 >= 0) & (iy1 < H);
        const bool vx0 = (ix0 >= 0) & (ix0 < W);
        const bool vx1 = (ix1 >= 0) & (ix1 < W);
        const float w00 = (vy0 & vx0) ? wy0 * wx0 * mm : 0.0f;
        const float w01 = (vy0 & vx1) ? wy0 * wx1 * mm : 0.0f;
        const float w10 = (vy1 & vx0) ? wy1 * wx0 * mm : 0.0f;
        const float w11 = (vy1 & vx1) ? wy1 * wx1 * mm : 0.0f;
        union { __half2 h2; unsigned u; } p01, p23;
        p01.h2 = __floats2half2_rn(w00, w01);
        p23.h2 = __floats2half2_rn(w10, w11);
        const int cy0 = min(max(iy0, 0), H - 1);
        const int cy1 = min(max(iy1, 0), H - 1);
        const int cx0 = min(max(ix0, 0), W - 1);
        const int cx1 = min(max(ix1, 0), W - 1);
        // linear pixel indices (< 16384) fit u16; producer shifts <<7 for bytes
        ushort4 bv;
        bv.x = (unsigned short)(cy0 * W + cx0);
        bv.y = (unsigned short)(cy0 * W + cx1);
        bv.z = (unsigned short)(cy1 * W + cx0);
        bv.w = (unsigned short)(cy1 * W + cx1);
        pidx[f] = bv;
        pwts[f] = uint2{p01.u, p23.u};
    }
    __syncthreads();                         // init barrier (full fence, once)

    if (wave < 2) {
        // ================= PRODUCER: sample -> LDS =================
        const int spx = tid >> 2;            // 0..31 pixel in tile
        const int cq  = (tid & 3) * 16;      // 16-channel quarter
        const char* xb =
            (const char*)(xt + (size_t)b * HW * C) + cq * 2;

        for (int k = 0; k < K2; ++k) {
            const ushort4 bi = pidx[k * TPX + spx];  // ds_read_b64 (4-px bcast)
            const uint2   wu = pwts[k * TPX + spx];  // ds_read_b64
            union HU { unsigned u; __half2 h2; };
            HU t01{wu.x}, t23{wu.y};
            const __half2 w0 = __half2half2(__low2half (t01.h2));
            const __half2 w1 = __half2half2(__high2half(t01.h2));
            const __half2 w2 = __half2half2(__low2half (t23.h2));
            const __half2 w3 = __half2half2(__high2half(t23.h2));
            const short* s00 = (const short*)(xb + ((int)bi.x << 7));
            const short* s01 = (const short*)(xb + ((int)bi.y << 7));
            const short* s10 = (const short*)(xb + ((int)bi.z << 7));
            const short* s11 = (const short*)(xb + ((int)bi.w << 7));

            short* dst = &smem[k & 1][spx * LDSS + cq];
#pragma unroll
            for (int h = 0; h < 2; ++h) {    // two 8-channel halves
                union U8 { short8 s; __half2 h2[4]; };
                const U8 g00{*(const short8*)(s00 + h * 8)};
                const U8 g01{*(const short8*)(s01 + h * 8)};
                const U8 g10{*(const short8*)(s10 + h * 8)};
                const U8 g11{*(const short8*)(s11 + h * 8)};
                U8 rr;
#pragma unroll
                for (int p = 0; p < 4; ++p) {
                    rr.h2[p] = __hfma2(g11.h2[p], w3,
                               __hfma2(g10.h2[p], w2,
                               __hfma2(g01.h2[p], w1,
                               __hmul2(g00.h2[p], w0))));
                }
                *(short8*)(dst + h * 8) = rr.s;
            }
            LDS_BARRIER();                   // tile k ready (lgkm drain only)
        }
    } else {
        // ====== CONSUMER: output-channel-partitioned LDS -> MFMA ======
        // wave w owns outputs [32w, 32w+32) (mt tiles 2w, 2w+1) for all 32 px.
        const int w    = wave - 2;           // 0..1 output half
        const int lane = tid & 63;
        const int col  = lane & 15;
        const int q    = lane >> 4;
        const f16x8* wf = (const f16x8*)wfrag;

        f32x4 acc[2][2];
#pragma unroll
        for (int m = 0; m < 2; ++m)
#pragma unroll
            for (int n = 0; n < 2; ++n) acc[m][n] = (f32x4)0.0f;

        f16x8 afa[4], afb[4];                // [m*2+kk], double-buffered
#pragma unroll
        for (int m = 0; m < 2; ++m)
#pragma unroll
            for (int kk = 0; kk < 2; ++kk)   // tap 0
                afa[m * 2 + kk] = wf[(kk * 4 + 2 * w + m) * 64 + lane];

#pragma unroll
        for (int k = 0; k < K2; ++k) {
            auto& af  = (k & 1) ? afb : afa;
            auto& afn = (k & 1) ? afa : afb;
            LDS_BARRIER();                   // wait tile k
            if (k + 1 < K2) {                // prefetch tap k+1's 4 A-frags
#pragma unroll
                for (int m = 0; m < 2; ++m)
#pragma unroll
                    for (int kk = 0; kk < 2; ++kk)
                        afn[m * 2 + kk] =
                            wf[((k + 1) * 8 + kk * 4 + 2 * w + m) * 64 + lane];
            }
#pragma unroll
            for (int kk = 0; kk < 2; ++kk) {
#pragma unroll
                for (int n = 0; n < 2; ++n) {
                    const f16x8 bfrag = *(const f16x8*)(
                        &smem[k & 1][(n * 16 + col) * LDSS + kk * 32 + q * 8]);
#pragma unroll
                    for (int m = 0; m < 2; ++m)
                        acc[m][n] = __builtin_amdgcn_mfma_f32_16x16x32_f16(
                            af[m * 2 + kk], bfrag, acc[m][n], 0, 0, 0);
                }
            }
        }

        // ---- epilogue: D row=(q*4+r) -> o = (2w+m)*16+q*4+r, col -> px ----
#pragma unroll
        for (int m = 0; m < 2; ++m) {
#pragma unroll
            for (int n = 0; n < 2; ++n) {
                const int wo = px0 + n * 16 + col;
#pragma unroll
                for (int r = 0; r < 4; ++r) {
                    const int o = (2 * w + m) * 16 + q * 4 + r;
                    out[(((size_t)b * COUT + o) * H + ho) * W + wo] =
                        acc[m][n][r] + bias[o];
                }
            }
        }
    }
}

// ---------- fallback (direct, no workspace) ----------
__global__ __launch_bounds__(256) void mdcn_direct_kernel(
    const float* __restrict__ x, const float* __restrict__ offset,
    const float* __restrict__ mask, const float* __restrict__ wsrc,
    const float* __restrict__ bias, float* __restrict__ out) {
    const int p  = blockIdx.x * blockDim.x + threadIdx.x;
    const int wo = p & (W - 1);
    const int ho = (p >> 7) & (H - 1);
    const int b  = p >> 14;
    float acc[COUT];
#pragma unroll
    for (int o = 0; o < COUT; ++o) acc[o] = bias[o];
    const float* xb = x + b * C * HW;
    for (int k = 0; k < K2; ++k) {
        const int ky = k / 3, kx = k % 3;
        const float dx = offset[((b * 2 * K2 + 2 * k    ) * H + ho) * W + wo];
        const float dy = offset[((b * 2 * K2 + 2 * k + 1) * H + ho) * W + wo];
        const float m  = mask  [((b * K2     + k        ) * H + ho) * W + wo];
        const float py = (float)(ho - 1 + ky) + dy;
        const float px = (float)(wo - 1 + kx) + dx;
        const float y0f = floorf(py), x0f = floorf(px);
        const float wy1 = py - y0f, wx1 = px - x0f;
        const float wy0 = 1.0f - wy1, wx0 = 1.0f - wx1;
        const int iy0 = (int)y0f, ix0 = (int)x0f;
        const int iy1 = iy0 + 1, ix1 = ix0 + 1;
        const bool vy0 = (iy0 >= 0) & (iy0 < H);
        const bool vy1 = (iy1 >= 0) & (iy1 < H);
        const bool vx0 = (ix0 >= 0) & (ix0 < W);
        const bool vx1 = (ix1 >= 0) & (ix1 < W);
        const float w00 = (vy0 & vx0) ? wy0 * wx0 * m : 0.0f;
        const float w01 = (vy0 & vx1) ? wy0 * wx1 * m : 0.0f;
        const float w10 = (vy1 & vx0) ? wy1 * wx0 * m : 0.0f;
        const float w11 = (vy1 & vx1) ? wy1 * wx1 * m : 0.0f;
        const int cy0 = min(max(iy0, 0), H - 1);
        const int cy1 = min(max(iy1, 0), H - 1);
        const int cx0 = min(max(ix0, 0), W - 1);
        const int cx1 = min(max(ix1, 0), W - 1);
        const int o00 = cy0 * W + cx0, o01 = cy0 * W + cx1;
        const int o10 = cy1 * W + cx0, o11 = cy1 * W + cx1;
        for (int c = 0; c < C; ++c) {
            const float* xp = xb + c * HW;
            const float val = w00 * xp[o00] + w01 * xp[o01] +
                              w10 * xp[o10] + w11 * xp[o11];
#pragma unroll
            for (int o = 0; o < COUT; ++o)
                acc[o] += wsrc[(o * C + c) * K2 + k] * val;
        }
    }
    float* op = out + ((size_t)b * COUT) * HW + ho * W + wo;
#pragma unroll
    for (int o = 0; o < COUT; ++o) op[o * HW] = acc[o];
}

extern "C" void kernel_launch(void* const* d_in, const int* in_sizes, int n_in,
                              void* d_out, int out_size, void* d_ws, size_t ws_size,
                              hipStream_t stream) {
    const float* x      = (const float*)d_in[0];
    const float* offset = (const float*)d_in[1];
    const float* mask   = (const float*)d_in[2];
    const float* weight = (const float*)d_in[3];
    const float* bias   = (const float*)d_in[4];
    float* out          = (float*)d_out;

    const size_t xt_bytes = (size_t)B * HW * C * sizeof(short);   // 16.78 MB
    const size_t wf_bytes = (size_t)COUT * C * K2 * sizeof(short);
    if (ws_size >= xt_bytes + wf_bytes) {
        short* xt    = (short*)d_ws;
        short* wfrag = (short*)((char*)d_ws + xt_bytes);
        transpose_x_kernel<<<B * (HW / 64), 256, 0, stream>>>(x, xt);
        pack_w_kernel<<<(COUT * C * K2 + 255) / 256, 256, 0, stream>>>(weight, wfrag);
        mdcn_pc_kernel<<<4 * B * H, 256, 0, stream>>>(xt, offset, mask, wfrag, bias, out);
    } else {
        mdcn_direct_kernel<<<(B * HW) / 256, 256, 0, stream>>>(
            x, offset, mask, weight, bias, out);
    }
}

// Round 11
// 135.240 us; speedup vs baseline: 1.0115x; 1.0115x over previous
//
#include <hip/hip_runtime.h>
#include <hip/hip_bf16.h>
#include <hip/hip_fp16.h>

// ModulatedDeformConv2d forward: f16 NHWC x, XCD-swizzled,
// producer/consumer wave-specialized fused sample+MFMA.
// R20 = R19 + 3-tap batches per barrier (6-slot LDS ring): the per-tap
// s_barrier was blocking compiler load-hoisting (loads never cross a
// barrier), serializing 8 gathers x ~300cy every tap. Within a batch the
// 3 taps' 24 gathers share one barrier-free window -> structural MLP x3.
// Barriers 18 -> 6. Consumer issues its batch's 12 A-frag loads BEFORE
// the barrier wait (vmcnt doesn't block s_barrier). launch_bounds(256,4)
// gives 128 VGPR for in-flight loads; LDS 32.3 KB -> 4 blocks/CU.
// x[8,64,128,128] f32, offset[8,18,128,128], mask[8,9,128,128],
// weight[64,64,3,3], bias[64]; out[8,64,128,128] f32.

constexpr int B    = 8;
constexpr int C    = 64;
constexpr int H    = 128;
constexpr int W    = 128;
constexpr int COUT = 64;
constexpr int K2   = 9;
constexpr int HW   = H * W;
constexpr int TPX  = 32;   // pixels per tile

typedef __attribute__((ext_vector_type(8))) short    short8;
typedef __attribute__((ext_vector_type(8))) _Float16 f16x8;
typedef __attribute__((ext_vector_type(4))) float    f32x4;

// LDS tile row: 64 ch padded to 72 halves (144 B).
constexpr int LDSS = 72;

// Raw workgroup barrier: drain LDS ops only (no vmcnt(0) drain).
#define LDS_BARRIER() asm volatile("s_waitcnt lgkmcnt(0)\n\ts_barrier" ::: "memory")

// ---------- x: NCHW f32 -> NHWC f16 ----------
__global__ __launch_bounds__(256) void transpose_x_kernel(
    const float* __restrict__ x, short* __restrict__ xt) {
    __shared__ float tbuf[64][65];
    const int blk  = blockIdx.x;          // B * (HW/64) = 2048
    const int b    = blk >> 8;
    const int hwb  = (blk & 255) * 64;
    const int lane = threadIdx.x & 63;
    const int grp  = threadIdx.x >> 6;    // 0..3
    const float* xb = x + (size_t)b * C * HW;
#pragma unroll
    for (int r = 0; r < 16; ++r) {
        const int c = grp * 16 + r;
        tbuf[c][lane] = xb[c * HW + hwb + lane];   // coalesced along hw
    }
    __syncthreads();
    short* xo = xt + (size_t)b * HW * C;
#pragma unroll
    for (int r = 0; r < 16; ++r) {
        const int hw_l = grp * 16 + r;
        union { __half h; short s; } u;
        u.h = __float2half(tbuf[lane][hw_l]);
        xo[(size_t)(hwb + hw_l) * C + lane] = u.s;  // coalesced along c
    }
}

// ---------- weight[o][c][3][3] f32 -> A-fragment-ordered f16 ----------
// wfrag[(k*8 + kk*4 + mt)*64 + lane][j] = f16( w[m][c][k] )
//   m = mt*16 + (lane&15), q = lane>>4, c = kk*32 + q*8 + j
__global__ __launch_bounds__(256) void pack_w_kernel(
    const float* __restrict__ w, short* __restrict__ wfrag) {
    int id = blockIdx.x * blockDim.x + threadIdx.x;
    if (id >= COUT * C * K2) return;
    const int j    = id & 7;
    const int lane = (id >> 3) & 63;
    const int mt   = (id >> 9) & 3;
    const int kk   = (id >> 11) & 1;
    const int k    = id >> 12;
    const int m    = mt * 16 + (lane & 15);
    const int q    = lane >> 4;
    const int c    = kk * 32 + q * 8 + j;
    union { __half h; short s; } u;
    u.h = __float2half(w[(m * C + c) * K2 + k]);
    wfrag[id] = u.s;
}

// ---------- producer/consumer fused kernel ----------
// grid 4096: b = wg&7 (XCD round-robin -> per-XCD-L2-resident f16 x),
// t = wg>>3 -> (ho, 32-px quarter-row). 256 threads = 4 waves.
__global__ __launch_bounds__(256, 4) void mdcn_pc_kernel(
    const short* __restrict__ xt,      // [B][H][W][C] f16
    const float* __restrict__ offset,
    const float* __restrict__ mask,
    const short* __restrict__ wfrag,
    const float* __restrict__ bias,
    float* __restrict__ out) {

    __shared__ short   smem[6][TPX * LDSS];  // 6-slot ring (2 batches x 3 taps)
    __shared__ ushort4 pidx[K2 * TPX];       // 2304 B: 4 corner linear indices
    __shared__ uint2   pwts[K2 * TPX];       // 2304 B: 4 blend wts as half4

    const int wg   = blockIdx.x;
    const int b    = wg & 7;
    const int t    = wg >> 3;                // 0..511
    const int ho   = t >> 2;
    const int px0  = (t & 3) * TPX;

    const int tid  = threadIdx.x;
    const int wave = tid >> 6;

    // ---- precompute ALL taps' sampling params (one thread per (tap,px)) ----
    for (int f = tid; f < K2 * TPX; f += 256) {
        const int k = f >> 5;                // tap
        const int i = f & 31;                // tile-local pixel
        const int wo = px0 + i;
        const int ky = k / 3, kx = k % 3;
        const float dx = offset[(((size_t)b * 2 * K2 + 2 * k    ) * H + ho) * W + wo];
        const float dy = offset[(((size_t)b * 2 * K2 + 2 * k + 1) * H + ho) * W + wo];
        const float mm = mask  [(((size_t)b * K2     + k        ) * H + ho) * W + wo];
        const float py = (float)(ho - 1 + ky) + dy;
        const float px = (float)(wo - 1 + kx) + dx;
        const float y0f = floorf(py), x0f = floorf(px);
        const float wy1 = py - y0f,   wx1 = px - x0f;
        const float wy0 = 1.0f - wy1, wx0 = 1.0f - wx1;
        const int iy0 = (int)y0f, ix0 = (int)x0f;
        const int iy1 = iy0 + 1,  ix1 = ix0 + 1;
        const bool vy0 = (iy0 >= 0) & (iy0 < H);
        const bool vy1 = (iy1 >= 0) & (iy1 < H);
        const bool vx0 = (ix0 >= 0) & (ix0 < W);
        const bool vx1 = (ix1 >= 0) & (ix1 < W);
        const float w00 = (vy0 & vx0) ? wy0 * wx0 * mm : 0.0f;
        const float w01 = (vy0 & vx1) ? wy0 * wx1 * mm : 0.0f;
        const float w10 = (vy1 & vx0) ? wy1 * wx0 * mm : 0.0f;
        const float w11 = (vy1 & vx1) ? wy1 * wx1 * mm : 0.0f;
        union { __half2 h2; unsigned u; } p01, p23;
        p01.h2 = __floats2half2_rn(w00, w01);
        p23.h2 = __floats2half2_rn(w10, w11);
        const int cy0 = min(max(iy0, 0), H - 1);
        const int cy1 = min(max(iy1, 0), H - 1);
        const int cx0 = min(max(ix0, 0), W - 1);
        const int cx1 = min(max(ix1, 0), W - 1);
        // linear pixel indices (< 16384) fit u16; producer shifts <<7 for bytes
        ushort4 bv;
        bv.x = (unsigned short)(cy0 * W + cx0);
        bv.y = (unsigned short)(cy0 * W + cx1);
        bv.z = (unsigned short)(cy1 * W + cx0);
        bv.w = (unsigned short)(cy1 * W + cx1);
        pidx[f] = bv;
        pwts[f] = uint2{p01.u, p23.u};
    }
    __syncthreads();                         // init barrier (full fence, once)

    if (wave < 2) {
        // ===== PRODUCER: 3-tap batched sample -> LDS (barrier-free window) ==
        const int spx = tid >> 2;            // 0..31 pixel in tile
        const int cq  = (tid & 3) * 16;      // 16-channel quarter
        const char* xb =
            (const char*)(xt + (size_t)b * HW * C) + cq * 2;

#pragma unroll
        for (int batch = 0; batch < 3; ++batch) {
            const int base  = batch * 3;
            const int sbase = (batch & 1) * 3;

            // params for all 3 taps of this batch
            ushort4 bi[3];
            uint2   wu[3];
#pragma unroll
            for (int tt = 0; tt < 3; ++tt) {
                bi[tt] = pidx[(base + tt) * TPX + spx];
                wu[tt] = pwts[(base + tt) * TPX + spx];
            }

            // issue ALL 24 gathers of the batch (no barrier in between)
            short8 g[3][8];
#pragma unroll
            for (int tt = 0; tt < 3; ++tt) {
                const short* s00 = (const short*)(xb + ((int)bi[tt].x << 7));
                const short* s01 = (const short*)(xb + ((int)bi[tt].y << 7));
                const short* s10 = (const short*)(xb + ((int)bi[tt].z << 7));
                const short* s11 = (const short*)(xb + ((int)bi[tt].w << 7));
                g[tt][0] = *(const short8*)(s00);
                g[tt][1] = *(const short8*)(s01);
                g[tt][2] = *(const short8*)(s10);
                g[tt][3] = *(const short8*)(s11);
                g[tt][4] = *(const short8*)(s00 + 8);
                g[tt][5] = *(const short8*)(s01 + 8);
                g[tt][6] = *(const short8*)(s10 + 8);
                g[tt][7] = *(const short8*)(s11 + 8);
            }

            // blend + write each tap to its ring slot
#pragma unroll
            for (int tt = 0; tt < 3; ++tt) {
                union HU { unsigned u; __half2 h2; };
                HU t01{wu[tt].x}, t23{wu[tt].y};
                const __half2 w0 = __half2half2(__low2half (t01.h2));
                const __half2 w1 = __half2half2(__high2half(t01.h2));
                const __half2 w2 = __half2half2(__low2half (t23.h2));
                const __half2 w3 = __half2half2(__high2half(t23.h2));
                short* dst = &smem[sbase + tt][spx * LDSS + cq];
#pragma unroll
                for (int h = 0; h < 2; ++h) {    // two 8-channel halves
                    union U8 { short8 s; __half2 h2[4]; };
                    const U8 g00{g[tt][h * 4 + 0]};
                    const U8 g01{g[tt][h * 4 + 1]};
                    const U8 g10{g[tt][h * 4 + 2]};
                    const U8 g11{g[tt][h * 4 + 3]};
                    U8 rr;
#pragma unroll
                    for (int p = 0; p < 4; ++p) {
                        rr.h2[p] = __hfma2(g11.h2[p], w3,
                                   __hfma2(g10.h2[p], w2,
                                   __hfma2(g01.h2[p], w1,
                                   __hmul2(g00.h2[p], w0))));
                    }
                    *(short8*)(dst + h * 8) = rr.s;
                }
            }
            LDS_BARRIER();                   // publish batch (3 tiles)
        }
    } else {
        // ====== CONSUMER: output-channel-partitioned LDS -> MFMA ======
        // wave w owns outputs [32w, 32w+32) (mt tiles 2w, 2w+1) for all 32 px.
        const int w    = wave - 2;           // 0..1 output half
        const int lane = tid & 63;
        const int col  = lane & 15;
        const int q    = lane >> 4;
        const f16x8* wf = (const f16x8*)wfrag;

        f32x4 acc[2][2];
#pragma unroll
        for (int m = 0; m < 2; ++m)
#pragma unroll
            for (int n = 0; n < 2; ++n) acc[m][n] = (f32x4)0.0f;

#pragma unroll
        for (int batch = 0; batch < 3; ++batch) {
            const int base  = batch * 3;
            const int sbase = (batch & 1) * 3;

            // issue this batch's 12 A-frag loads BEFORE the barrier wait:
            // vmcnt doesn't block s_barrier -> loads complete during the wait.
            f16x8 af[3][4];
#pragma unroll
            for (int tt = 0; tt < 3; ++tt)
#pragma unroll
                for (int m = 0; m < 2; ++m)
#pragma unroll
                    for (int kk = 0; kk < 2; ++kk)
                        af[tt][m * 2 + kk] =
                            wf[((base + tt) * 8 + kk * 4 + 2 * w + m) * 64 + lane];

            LDS_BARRIER();                   // wait for batch's 3 tiles

#pragma unroll
            for (int tt = 0; tt < 3; ++tt) {
#pragma unroll
                for (int kk = 0; kk < 2; ++kk) {
#pragma unroll
                    for (int n = 0; n < 2; ++n) {
                        const f16x8 bfrag = *(const f16x8*)(
                            &smem[sbase + tt][(n * 16 + col) * LDSS + kk * 32 + q * 8]);
#pragma unroll
                        for (int m = 0; m < 2; ++m)
                            acc[m][n] = __builtin_amdgcn_mfma_f32_16x16x32_f16(
                                af[tt][m * 2 + kk], bfrag, acc[m][n], 0, 0, 0);
                    }
                }
            }
        }

        // ---- epilogue: D row=(q*4+r) -> o = (2w+m)*16+q*4+r, col -> px ----
#pragma unroll
        for (int m = 0; m < 2; ++m) {
#pragma unroll
            for (int n = 0; n < 2; ++n) {
                const int wo = px0 + n * 16 + col;
#pragma unroll
                for (int r = 0; r < 4; ++r) {
                    const int o = (2 * w + m) * 16 + q * 4 + r;
                    out[(((size_t)b * COUT + o) * H + ho) * W + wo] =
                        acc[m][n][r] + bias[o];
                }
            }
        }
    }
}

// ---------- fallback (direct, no workspace) ----------
__global__ __launch_bounds__(256) void mdcn_direct_kernel(
    const float* __restrict__ x, const float* __restrict__ offset,
    const float* __restrict__ mask, const float* __restrict__ wsrc,
    const float* __restrict__ bias, float* __restrict__ out) {
    const int p  = blockIdx.x * blockDim.x + threadIdx.x;
    const int wo = p & (W - 1);
    const int ho = (p >> 7) & (H - 1);
    const int b  = p >> 14;
    float acc[COUT];
#pragma unroll
    for (int o = 0; o < COUT; ++o) acc[o] = bias[o];
    const float* xb = x + b * C * HW;
    for (int k = 0; k < K2; ++k) {
        const int ky = k / 3, kx = k % 3;
        const float dx = offset[((b * 2 * K2 + 2 * k    ) * H + ho) * W + wo];
        const float dy = offset[((b * 2 * K2 + 2 * k + 1) * H + ho) * W + wo];
        const float m  = mask  [((b * K2     + k        ) * H + ho) * W + wo];
        const float py = (float)(ho - 1 + ky) + dy;
        const float px = (float)(wo - 1 + kx) + dx;
        const float y0f = floorf(py), x0f = floorf(px);
        const float wy1 = py - y0f, wx1 = px - x0f;
        const float wy0 = 1.0f - wy1, wx0 = 1.0f - wx1;
        const int iy0 = (int)y0f, ix0 = (int)x0f;
        const int iy1 = iy0 + 1, ix1 = ix0 + 1;
        const bool vy0 = (iy0 >= 0) & (iy0 < H);
        const bool vy1 = (iy1 >= 0) & (iy1 < H);
        const bool vx0 = (ix0 >= 0) & (ix0 < W);
        const bool vx1 = (ix1 >= 0) & (ix1 < W);
        const float w00 = (vy0 & vx0) ? wy0 * wx0 * m : 0.0f;
        const float w01 = (vy0 & vx1) ? wy0 * wx1 * m : 0.0f;
        const float w10 = (vy1 & vx0) ? wy1 * wx0 * m : 0.0f;
        const float w11 = (vy1 & vx1) ? wy1 * wx1 * m : 0.0f;
        const int cy0 = min(max(iy0, 0), H - 1);
        const int cy1 = min(max(iy1, 0), H - 1);
        const int cx0 = min(max(ix0, 0), W - 1);
        const int cx1 = min(max(ix1, 0), W - 1);
        const int o00 = cy0 * W + cx0, o01 = cy0 * W + cx1;
        const int o10 = cy1 * W + cx0, o11 = cy1 * W + cx1;
        for (int c = 0; c < C; ++c) {
            const float* xp = xb + c * HW;
            const float val = w00 * xp[o00] + w01 * xp[o01] +
                              w10 * xp[o10] + w11 * xp[o11];
#pragma unroll
            for (int o = 0; o < COUT; ++o)
                acc[o] += wsrc[(o * C + c) * K2 + k] * val;
        }
    }
    float* op = out + ((size_t)b * COUT) * HW + ho * W + wo;
#pragma unroll
    for (int o = 0; o < COUT; ++o) op[o * HW] = acc[o];
}

extern "C" void kernel_launch(void* const* d_in, const int* in_sizes, int n_in,
                              void* d_out, int out_size, void* d_ws, size_t ws_size,
                              hipStream_t stream) {
    const float* x      = (const float*)d_in[0];
    const float* offset = (const float*)d_in[1];
    const float* mask   = (const float*)d_in[2];
    const float* weight = (const float*)d_in[3];
    const float* bias   = (const float*)d_in[4];
    float* out          = (float*)d_out;

    const size_t xt_bytes = (size_t)B * HW * C * sizeof(short);   // 16.78 MB
    const size_t wf_bytes = (size_t)COUT * C * K2 * sizeof(short);
    if (ws_size >= xt_bytes + wf_bytes) {
        short* xt    = (short*)d_ws;
        short* wfrag = (short*)((char*)d_ws + xt_bytes);
        transpose_x_kernel<<<B * (HW / 64), 256, 0, stream>>>(x, xt);
        pack_w_kernel<<<(COUT * C * K2 + 255) / 256, 256, 0, stream>>>(weight, wfrag);
        mdcn_pc_kernel<<<4 * B * H, 256, 0, stream>>>(xt, offset, mask, wfrag, bias, out);
    } else {
        mdcn_direct_kernel<<<(B * HW) / 256, 256, 0, stream>>>(
            x, offset, mask, weight, bias, out);
    }
}